// Round 3
// baseline (171.372 us; speedup 1.0000x reference)
//
#include <hip/hip_runtime.h>

// out[i] = floor(image[i] * 0.5f) — pure elementwise stream, memory-bound.
// image: 8*3*1024*1024 fp32 (25,165,824 elements = 6,291,456 float4s).
// Compulsory traffic: 96 MiB read + 96 MiB write = 192 MiB → ~30 µs @ 6.3 TB/s.
//
// Harness anatomy (decoded from rocprof rounds 0-2): each timed iteration =
// two 384 MiB poison fills (~120 µs, harness-owned, 6.8 TB/s) + this kernel.
// Round-1 counters showed FETCH_SIZE = 48 MiB with cached loads: HALF the
// 96 MiB input survives the fills in the 256 MiB LLC. So:
//   - loads: plain cached (harvest the ~50% L3 residency across replays)
//   - stores: nontemporal (output is read once by the checker then
//     re-poisoned; caching it only evicts the input we want resident)
//
// Kernel shape: monolithic one-float4-per-thread, no loop (round 2's best) —
// same shape as the 6.8 TB/s fill kernel. 24,576 blocks of 256.
//
// NOTE: __builtin_nontemporal_* rejects HIP_vector_type structs; use a native
// clang ext_vector_type float4 (identical 16B layout/alignment).

typedef float vfloat4 __attribute__((ext_vector_type(4)));

__global__ __launch_bounds__(256) void stego_halve(const vfloat4* __restrict__ in,
                                                   vfloat4* __restrict__ out,
                                                   int n4) {
    int i = blockIdx.x * 256 + threadIdx.x;
    if (i < n4) {
        vfloat4 v = in[i];                     // cached: exploit L3 residency
        vfloat4 r;
        r.x = floorf(v.x * 0.5f);
        r.y = floorf(v.y * 0.5f);
        r.z = floorf(v.z * 0.5f);
        r.w = floorf(v.w * 0.5f);
        __builtin_nontemporal_store(r, &out[i]);  // evict-first: one-shot output
    }
}

__global__ __launch_bounds__(256) void stego_halve_tail(const float* __restrict__ in,
                                                        float* __restrict__ out,
                                                        int start, int n) {
    int i = start + blockIdx.x * 256 + threadIdx.x;
    if (i < n) {
        out[i] = floorf(in[i] * 0.5f);
    }
}

extern "C" void kernel_launch(void* const* d_in, const int* in_sizes, int n_in,
                              void* d_out, int out_size, void* d_ws, size_t ws_size,
                              hipStream_t stream) {
    const float* image = (const float*)d_in[0];
    float* out = (float*)d_out;
    int n = in_sizes[0];   // 25,165,824

    int n4 = n / 4;        // 6,291,456 float4s
    int tail_start = n4 * 4;

    if (n4 > 0) {
        const int block = 256;
        int grid = (n4 + block - 1) / block;   // 24,576 for the bench shape
        stego_halve<<<grid, block, 0, stream>>>((const vfloat4*)image,
                                                (vfloat4*)out, n4);
    }
    if (tail_start < n) {
        int rem = n - tail_start;
        const int block = 256;
        int grid = (rem + block - 1) / block;
        stego_halve_tail<<<grid, block, 0, stream>>>(image, out, tail_start, n);
    }
}

// Round 4
// 167.238 us; speedup vs baseline: 1.0247x; 1.0247x over previous
//
#include <hip/hip_runtime.h>

// out[i] = floor(image[i] * 0.5f) — pure elementwise stream, memory-bound.
// image: 8*3*1024*1024 fp32 (25,165,824 elements = 6,291,456 float4s).
// Compulsory traffic: 96 MiB read + 96 MiB write = 192 MiB → ~30 µs @ 6.3 TB/s.
//
// Harness anatomy (decoded rounds 0-3): each timed iteration = two 384 MiB
// poison fills (~120 µs, harness-owned, 6.8 TB/s) + this kernel. The fills
// thrash the 256 MiB LLC; R3's A/B showed cached loads LOSE to NT loads
// (51 vs 46 µs) despite ~48 MiB L3 residency — so NT on BOTH paths.
//
// Kernel shape: deep-batch streaming. Each block owns a contiguous 32 KiB
// chunk (2048 float4s); each thread handles 8 float4s at +256 stride
// (wave-contiguous 1 KiB per instruction). The 8 NT loads are issued
// back-to-back (8-deep memory-level parallelism per wave), then 8 NT
// stores. 3072 blocks (12/CU) = 8x fewer wave setups than the monolithic
// 1-float4/thread version (R2, ~46 µs), whose waves did only 1 KiB in /
// 1 KiB out each.
//
// NOTE: __builtin_nontemporal_* rejects HIP_vector_type structs; use a native
// clang ext_vector_type float4 (identical 16B layout/alignment).

typedef float vfloat4 __attribute__((ext_vector_type(4)));

#define VEC 8            // float4s per thread
#define BLOCK 256
#define CHUNK (VEC * BLOCK)   // 2048 float4s = 32 KiB per block-chunk

__device__ __forceinline__ vfloat4 halve_floor4(vfloat4 v) {
    vfloat4 r;
    r.x = floorf(v.x * 0.5f);
    r.y = floorf(v.y * 0.5f);
    r.z = floorf(v.z * 0.5f);
    r.w = floorf(v.w * 0.5f);
    return r;
}

__global__ __launch_bounds__(BLOCK) void stego_halve(const vfloat4* __restrict__ in,
                                                     vfloat4* __restrict__ out,
                                                     int n4) {
    const int tid = threadIdx.x;
    // chunk-stride outer loop (runs exactly once per block for the bench shape)
    for (int base = blockIdx.x * CHUNK; base < n4; base += gridDim.x * CHUNK) {
        const int i0 = base + tid;
        if (base + CHUNK <= n4) {
            // fast path: full chunk. 8 NT loads clustered, then 8 NT stores.
            vfloat4 v[VEC];
            #pragma unroll
            for (int k = 0; k < VEC; ++k)
                v[k] = __builtin_nontemporal_load(&in[i0 + k * BLOCK]);
            #pragma unroll
            for (int k = 0; k < VEC; ++k)
                __builtin_nontemporal_store(halve_floor4(v[k]), &out[i0 + k * BLOCK]);
        } else {
            // ragged last chunk (not taken for the bench shape)
            #pragma unroll
            for (int k = 0; k < VEC; ++k) {
                int i = i0 + k * BLOCK;
                if (i < n4)
                    __builtin_nontemporal_store(
                        halve_floor4(__builtin_nontemporal_load(&in[i])), &out[i]);
            }
        }
    }
}

__global__ __launch_bounds__(BLOCK) void stego_halve_tail(const float* __restrict__ in,
                                                          float* __restrict__ out,
                                                          int start, int n) {
    int i = start + blockIdx.x * BLOCK + threadIdx.x;
    if (i < n) {
        out[i] = floorf(in[i] * 0.5f);
    }
}

extern "C" void kernel_launch(void* const* d_in, const int* in_sizes, int n_in,
                              void* d_out, int out_size, void* d_ws, size_t ws_size,
                              hipStream_t stream) {
    const float* image = (const float*)d_in[0];
    float* out = (float*)d_out;
    int n = in_sizes[0];   // 25,165,824

    int n4 = n / 4;        // 6,291,456 float4s
    int tail_start = n4 * 4;

    if (n4 > 0) {
        int nchunks = (n4 + CHUNK - 1) / CHUNK;   // 3072 for the bench shape
        int grid = nchunks > 16384 ? 16384 : nchunks;
        stego_halve<<<grid, BLOCK, 0, stream>>>((const vfloat4*)image,
                                                (vfloat4*)out, n4);
    }
    if (tail_start < n) {
        int rem = n - tail_start;
        int grid = (rem + BLOCK - 1) / BLOCK;
        stego_halve_tail<<<grid, BLOCK, 0, stream>>>(image, out, tail_start, n);
    }
}